// Round 8
// baseline (471.463 us; speedup 1.0000x reference)
//
#include <hip/hip_runtime.h>

// Problem: ExodusModel_8564164788248
// inp: (8,2,256,256,64) f32, w0: (4,2,7,7), w1: (8,4,7,7), wl: (2,128)
// out: (8,2,64) f32
//
// Workspace layout (floats):
//   pooled0 : (8,2,64,64,64)  = 4,194,304   @ 0
//   pooled1 : (8,4,16,16,64)  =   524,288   @ 12,582,912
//   h1      : (8,8,16,16,64)  = 1,048,576   @ 13,107,200  (s1 never stored)
//   feat    : (8,128,64)      =    65,536   @ 14,155,776
//   (h0 is never materialized: conv0 -> IAF0 -> pool1 is fused via LDS)

#define OFF_P0   0
#define OFF_P1   12582912
#define OFF_H1   13107200
#define OFF_FT   14155776

typedef float f32x4 __attribute__((ext_vector_type(4)));

// ---------------------------------------------------------------------------
// K1: avgpool 4x4 on raw input. (n,c,256,256,t) -> (n,c,64,64,t)
// float4 on stride-1 t axis; fp64 accumulate (exact /16). HBM-floor bound.
__global__ __launch_bounds__(256) void pool0_kernel(
        const float* __restrict__ inp, float* __restrict__ out) {
    int tid = blockIdx.x * blockDim.x + threadIdx.x;   // 1,048,576 threads
    int t4 = tid & 15;
    int px = (tid >> 4) & 63;
    int py = (tid >> 10) & 63;
    int nc = tid >> 16;                                // n*2+c, 0..15
    const float* base = inp + (size_t)nc * 4194304 + (size_t)t4 * 4;
    int y0 = py * 4, x0 = px * 4;
    double a0 = 0, a1 = 0, a2 = 0, a3 = 0;
    #pragma unroll
    for (int dy = 0; dy < 4; ++dy) {
        const float* row = base + ((size_t)(y0 + dy) * 256 + x0) * 64;
        #pragma unroll
        for (int dx = 0; dx < 4; ++dx) {
            const f32x4 v = __builtin_nontemporal_load(
                (const f32x4*)(row + dx * 64));
            a0 += (double)v.x; a1 += (double)v.y;
            a2 += (double)v.z; a3 += (double)v.w;
        }
    }
    float4 o = make_float4((float)(a0 * 0.0625), (float)(a1 * 0.0625),
                           (float)(a2 * 0.0625), (float)(a3 * 0.0625));
    ((float4*)out)[tid] = o;
}

// ---------------------------------------------------------------------------
// K2 v2: FUSED conv0 + IAF0 + pool1. h0 never hits HBM.
// Grid = 1024 blocks x 512 threads, ~36 KB LDS.
// Tile: oc 0..3, py = pyo*4..+3, px = pxb*8..+7, t 0..63.
//
// Phase 1 (conv): thread = t4(16) x pxl(8) x pr(4); ONE output row per
// thread (acc[4][4] = 32 VGPR, half of v1's 64 — spill-pressure relief).
// Interior blocks (pyo 1..14, pxb 1..6 = 66%) take a branch-free path with
// one address per (ic,ky); the 7 kx loads fold to immediate offsets.
// Per-output tap order (ic,ky,kx) ascending == previous versions =>
// bit-identical h0 values. LDS scatter rotation p*64+(t+p)&63 unchanged
// (pr == pp*2+row of v1).
// Phase 2 (IAF+pool): identical to v1: 128 threads scan their stream,
// byte-pack spikes, shfl_xor(1,2,8,16), coalesced float4 stores.
__global__ __launch_bounds__(512) void conv0_iaf0_pool1_kernel(
        const float* __restrict__ pooled0, const float* __restrict__ w0,
        float* __restrict__ pooled1) {
    __shared__ double w[392];                          // [oc*98 + ic*49 + ky*7 + kx]
    __shared__ float tile[8192];                       // [p 128][t 64], t rotated by p

    for (int i = threadIdx.x; i < 392; i += blockDim.x) w[i] = (double)w0[i];

    int b   = blockIdx.x;                              // (n 8)(pyo 16)(pxb 8)
    int pxb = b & 7;
    int pyo = (b >> 3) & 15;
    int n   = b >> 7;

    int tid = threadIdx.x;
    int t4  = tid & 15;
    int pxl = (tid >> 4) & 7;
    int pr  = tid >> 7;                                // 0..3: row within tile
    int px  = pxb * 8 + pxl;
    int py  = pyo * 4 + pr;

    __syncthreads();                                   // weights ready

    double acc[4][4] = {};                             // [oc][t]
    bool interior = (pyo >= 1) & (pyo <= 14) & (pxb >= 1) & (pxb <= 6);
    if (interior) {
        for (int ic = 0; ic < 2; ++ic) {
            const float* in_c = pooled0 + (size_t)(n * 2 + ic) * 262144
                              + (size_t)t4 * 4 + (size_t)(px - 3) * 64;
            const double* wic = w + ic * 49;           // + oc*98 + ky*7 + kx
            #pragma unroll
            for (int ky = 0; ky < 7; ++ky) {
                const float* in_row = in_c + (size_t)(py - 3 + ky) * 4096;
                #pragma unroll
                for (int kx = 0; kx < 7; ++kx) {
                    float4 v = *(const float4*)(in_row + kx * 64);
                    #pragma unroll
                    for (int oc = 0; oc < 4; ++oc) {
                        double wd = wic[oc * 98 + ky * 7 + kx];
                        acc[oc][0] += (double)v.x * wd;
                        acc[oc][1] += (double)v.y * wd;
                        acc[oc][2] += (double)v.z * wd;
                        acc[oc][3] += (double)v.w * wd;
                    }
                }
            }
        }
    } else {
        for (int ic = 0; ic < 2; ++ic) {
            const float* in_c = pooled0 + (size_t)(n * 2 + ic) * 262144
                              + (size_t)t4 * 4;
            const double* wic = w + ic * 49;
            #pragma unroll
            for (int ky = 0; ky < 7; ++ky) {
                int iy = py - 3 + ky;
                if (iy < 0 || iy >= 64) continue;
                const float* in_row = in_c + (size_t)iy * 4096;
                #pragma unroll
                for (int kx = 0; kx < 7; ++kx) {
                    int ix = px + kx - 3;
                    if (ix < 0 || ix >= 64) continue;
                    float4 v = *(const float4*)(in_row + ix * 64);
                    #pragma unroll
                    for (int oc = 0; oc < 4; ++oc) {
                        double wd = wic[oc * 98 + ky * 7 + kx];
                        acc[oc][0] += (double)v.x * wd;
                        acc[oc][1] += (double)v.y * wd;
                        acc[oc][2] += (double)v.z * wd;
                        acc[oc][3] += (double)v.w * wd;
                    }
                }
            }
        }
    }
    // scatter to LDS, rotated: idx = p*64 + (t+p)&63  (pr == v1's pyl)
    #pragma unroll
    for (int oc = 0; oc < 4; ++oc) {
        int p = oc * 32 + pr * 8 + pxl;
        #pragma unroll
        for (int j = 0; j < 4; ++j) {
            int tt = t4 * 4 + j;
            tile[p * 64 + ((tt + p) & 63)] = (float)acc[oc][j];
        }
    }
    __syncthreads();

    if (tid < 128) {
        int p   = tid;                                 // oc(2b at 5)|pyl(2b at 3)|pxl(3b)
        int oc  = p >> 5;
        int pxo = (p >> 2) & 1;
        float v = 0.f;
        unsigned int sp[16];
        const float* tp = tile + p * 64;
        #pragma unroll
        for (int i = 0; i < 16; ++i) {
            unsigned int wd = 0;
            #pragma unroll
            for (int j = 0; j < 4; ++j) {
                int t = i * 4 + j;
                float x = tp[(t + p) & 63];
                v += x;
                unsigned int s_ = (v >= 1.f) ? 1u : 0u;
                v -= (float)s_;
                wd += s_ << (8 * j);
            }
            sp[i] = wd;
        }
        // pool over dx (bits 0,1) and dy (bits 3,4); bytes can't carry
        #pragma unroll
        for (int i = 0; i < 16; ++i) {
            sp[i] += __shfl_xor(sp[i], 1);
            sp[i] += __shfl_xor(sp[i], 2);
            sp[i] += __shfl_xor(sp[i], 8);
            sp[i] += __shfl_xor(sp[i], 16);
        }
        int i = (p & 3) | (((p >> 3) & 3) << 2);       // member index 0..15
        unsigned int s = sp[i];
        float4 o = make_float4((float)(s & 255u)         * 0.0625f,
                               (float)((s >> 8)  & 255u) * 0.0625f,
                               (float)((s >> 16) & 255u) * 0.0625f,
                               (float)((s >> 24) & 255u) * 0.0625f);
        float* outp = pooled1 +
            (((size_t)(n * 4 + oc) * 16 + pyo) * 16 + (pxb * 2 + pxo)) * 64 + i * 4;
        *(float4*)outp = o;
    }
}

// ---------------------------------------------------------------------------
// K3 v2: conv7 pad3, ic=4 -> oc=8 on (8,4,16,16,t). fp64 accumulate, same tap
// order (ic,ky,kx ascending) as before => bit-identical h1.
// Each thread: 4 t-values (float4 load) x 4 oc. Grid: 256 blocks x 256.
__global__ __launch_bounds__(256) void conv1_kernel(
        const float* __restrict__ pooled1,
        const float* __restrict__ w1,
        float* __restrict__ h1) {
    __shared__ double w[1568];                         // (8,4,7,7)
    for (int i = threadIdx.x; i < 1568; i += blockDim.x) w[i] = (double)w1[i];
    __syncthreads();

    int tid = blockIdx.x * blockDim.x + threadIdx.x;   // 65,536 threads
    int t4 = tid & 15;                                 // 4 t per thread
    int px = (tid >> 4) & 15;
    int py = (tid >> 8) & 15;
    int og = (tid >> 12) & 1;                          // oc group: og*4 .. og*4+3
    int n  = tid >> 13;                                // 0..7

    double acc[4][4] = {};                             // [oc4][t j]

    for (int ic = 0; ic < 4; ++ic) {
        const float* in_c = pooled1 + (size_t)(n * 4 + ic) * 16384 + t4 * 4;
        const double* wic = w + (size_t)og * 4 * 196 + ic * 49;  // + oc4*196 + ky*7 + kx
        #pragma unroll
        for (int ky = 0; ky < 7; ++ky) {
            int iy = py + ky - 3;
            if (iy < 0 || iy >= 16) continue;
            const float* in_row = in_c + (size_t)iy * 1024;
            #pragma unroll
            for (int kx = 0; kx < 7; ++kx) {
                int ix = px + kx - 3;
                if (ix < 0 || ix >= 16) continue;
                float4 v = *(const float4*)(in_row + ix * 64);
                #pragma unroll
                for (int oc4 = 0; oc4 < 4; ++oc4) {
                    double wd = wic[oc4 * 196 + ky * 7 + kx];
                    acc[oc4][0] += (double)v.x * wd;
                    acc[oc4][1] += (double)v.y * wd;
                    acc[oc4][2] += (double)v.z * wd;
                    acc[oc4][3] += (double)v.w * wd;
                }
            }
        }
    }
    size_t ob = (size_t)n * 131072 + (size_t)(og * 4) * 16384
              + (size_t)py * 1024 + px * 64 + t4 * 4;
    #pragma unroll
    for (int oc4 = 0; oc4 < 4; ++oc4) {
        float4 o = make_float4((float)acc[oc4][0], (float)acc[oc4][1],
                               (float)acc[oc4][2], (float)acc[oc4][3]);
        *(float4*)(h1 + ob + (size_t)oc4 * 16384) = o;
    }
}

// ---------------------------------------------------------------------------
// K4: fused IAF1 + avgpool4 -> feat(n,128,t). Spikes never hit memory.
__global__ __launch_bounds__(256) void iaf1_pool2_kernel(
        const float* __restrict__ h1, float* __restrict__ feat) {
    int b = blockIdx.x;                                // 64 = (n 8)(c 8)
    int c = b & 7;
    int n = b >> 3;
    int tid = threadIdx.x;
    int dx  = tid & 3;
    int dy  = (tid >> 2) & 3;
    int q   = tid >> 4;                                // 0..15 = pyo*4+pxo
    int pyo = q >> 2;
    int pxo = q & 3;
    int py  = pyo * 4 + dy;
    int px  = pxo * 4 + dx;

    const float4* p = (const float4*)(h1 +
        (((size_t)(n * 8 + c) * 16 + py) * 16 + px) * 64);

    float v = 0.f;
    unsigned int sp[16];
    #pragma unroll
    for (int i = 0; i < 16; ++i) {
        float4 x = p[i];
        unsigned int w = 0;
        #define STEP(j, e)                                                    \
        {   v += x.e;                                                         \
            unsigned int s_ = (v >= 1.f) ? 1u : 0u;                           \
            v -= (float)s_;                                                   \
            w += s_ << (8 * j); }
        STEP(0, x) STEP(1, y) STEP(2, z) STEP(3, w)
        #undef STEP
        sp[i] = w;
    }
    #pragma unroll
    for (int i = 0; i < 16; ++i) {
        sp[i] += __shfl_xor(sp[i], 1);
        sp[i] += __shfl_xor(sp[i], 2);
        sp[i] += __shfl_xor(sp[i], 4);
        sp[i] += __shfl_xor(sp[i], 8);
    }
    int i = tid & 15;
    unsigned int s = sp[i];
    float4 o = make_float4((float)(s & 255u)         * 0.0625f,
                           (float)((s >> 8)  & 255u) * 0.0625f,
                           (float)((s >> 16) & 255u) * 0.0625f,
                           (float)((s >> 24) & 255u) * 0.0625f);
    int f = c * 16 + q;
    *(float4*)(feat + ((size_t)n * 128 + f) * 64 + i * 4) = o;
}

// ---------------------------------------------------------------------------
// K5: linear. out(n,j,t) = sum_f wl[j,f] * feat[n,f,t], fp64 acc, f ascending
// => bit-identical out.
__global__ __launch_bounds__(64) void linear_kernel(
        const float* __restrict__ feat, const float* __restrict__ wl,
        float* __restrict__ out) {
    int tid = blockIdx.x * 64 + threadIdx.x;           // 1024 threads
    int t = tid & 63;
    int j = (tid >> 6) & 1;
    int n = tid >> 7;
    const float* fp = feat + (size_t)n * 128 * 64 + t;
    const float* wp = wl + j * 128;
    double acc = 0.0;
    for (int f = 0; f < 128; ++f)
        acc += (double)wp[f] * (double)fp[(size_t)f * 64];
    out[(size_t)(n * 2 + j) * 64 + t] = (float)acc;
}

// ---------------------------------------------------------------------------
extern "C" void kernel_launch(void* const* d_in, const int* in_sizes, int n_in,
                              void* d_out, int out_size, void* d_ws, size_t ws_size,
                              hipStream_t stream) {
    const float* inp = (const float*)d_in[0];
    const float* w0  = (const float*)d_in[1];
    const float* w1  = (const float*)d_in[2];
    const float* wl  = (const float*)d_in[3];
    float* out = (float*)d_out;
    float* ws  = (float*)d_ws;

    float* pooled0 = ws + OFF_P0;
    float* pooled1 = ws + OFF_P1;
    float* h1      = ws + OFF_H1;
    float* feat    = ws + OFF_FT;

    pool0_kernel<<<4096, 256, 0, stream>>>(inp, pooled0);
    conv0_iaf0_pool1_kernel<<<1024, 512, 0, stream>>>(pooled0, w0, pooled1);
    conv1_kernel<<<256, 256, 0, stream>>>(pooled1, w1, h1);
    iaf1_pool2_kernel<<<64, 256, 0, stream>>>(h1, feat);
    linear_kernel<<<16, 64, 0, stream>>>(feat, wl, out);
}

// Round 9
// 453.967 us; speedup vs baseline: 1.0385x; 1.0385x over previous
//
#include <hip/hip_runtime.h>

// Problem: ExodusModel_8564164788248
// inp: (8,2,256,256,64) f32, w0: (4,2,7,7), w1: (8,4,7,7), wl: (2,128)
// out: (8,2,64) f32
//
// ROUND 8 FINDING (hardware A/B): conv fp64 was the wall. gfx950 fp64 VALU
// measures ~1 FMA/SIMD/cycle (~2.45e12 FMA/s chip-wide): 1.03G fp64 FMA
// == ~420 us of the 459-471 us total. K2 v1 (256thr) vs v2 (512thr) within
// 1.5% => structure-insensitive, pure fp64-issue-bound.
// => This version: conv0/conv1/pool0 accumulate in FP32 (78.6e12 FMA/s).
// The reference is fp32 XLA; our previous absmax 0.001953125 was already
// spike-flip noise vs that fp32 reference. fp32 here decorrelates the flip
// set; expected absmax ~0.003-0.008. Fallback if tolerance fails:
// double-float (TwoProd/TwoSum) conv, restores absmax exactly.
//
// Workspace layout (floats):
//   pooled0 : (8,2,64,64,64)  = 4,194,304   @ 0
//   pooled1 : (8,4,16,16,64)  =   524,288   @ 12,582,912
//   h1      : (8,8,16,16,64)  = 1,048,576   @ 13,107,200  (s1 never stored)
//   feat    : (8,128,64)      =    65,536   @ 14,155,776

#define OFF_P0   0
#define OFF_P1   12582912
#define OFF_H1   13107200
#define OFF_FT   14155776

typedef float f32x4 __attribute__((ext_vector_type(4)));

// ---------------------------------------------------------------------------
// K1: avgpool 4x4 on raw input. (n,c,256,256,t) -> (n,c,64,64,t)
// float4 on stride-1 t axis; fp32 accumulate + *0.0625 (matches reference's
// own fp32 mean; removes 67M fp64 adds from the derated fp64 pipe).
// HBM-floor bound (~285 MB => ~43 us at 6.7 TB/s).
__global__ __launch_bounds__(256) void pool0_kernel(
        const float* __restrict__ inp, float* __restrict__ out) {
    int tid = blockIdx.x * blockDim.x + threadIdx.x;   // 1,048,576 threads
    int t4 = tid & 15;
    int px = (tid >> 4) & 63;
    int py = (tid >> 10) & 63;
    int nc = tid >> 16;                                // n*2+c, 0..15
    const float* base = inp + (size_t)nc * 4194304 + (size_t)t4 * 4;
    int y0 = py * 4, x0 = px * 4;
    float a0 = 0.f, a1 = 0.f, a2 = 0.f, a3 = 0.f;
    #pragma unroll
    for (int dy = 0; dy < 4; ++dy) {
        const float* row = base + ((size_t)(y0 + dy) * 256 + x0) * 64;
        #pragma unroll
        for (int dx = 0; dx < 4; ++dx) {
            const f32x4 v = __builtin_nontemporal_load(
                (const f32x4*)(row + dx * 64));
            a0 += v.x; a1 += v.y; a2 += v.z; a3 += v.w;
        }
    }
    float4 o = make_float4(a0 * 0.0625f, a1 * 0.0625f,
                           a2 * 0.0625f, a3 * 0.0625f);
    ((float4*)out)[tid] = o;
}

// ---------------------------------------------------------------------------
// K2 v3: FUSED conv0 + IAF0 + pool1, FP32 taps. h0 never hits HBM.
// Structure == hardware-verified v2 (round 8, passed, bit-identical-to-v1):
// Grid = 1024 blocks x 512 threads, ~34 KB LDS.
// Phase 1: thread = t4(16) x pxl(8) x pr(4); one output row, acc[4][4] f32.
// Interior blocks (pyo 1..14, pxb 1..6 = 66%) branch-free. Tap order
// (ic,ky,kx) ascending per output.
// Phase 2 (IAF+pool): UNCHANGED — exact reference fp32 IAF sequence,
// byte-packed spikes, shfl_xor(1,2,8,16), coalesced float4 stores.
__global__ __launch_bounds__(512) void conv0_iaf0_pool1_kernel(
        const float* __restrict__ pooled0, const float* __restrict__ w0,
        float* __restrict__ pooled1) {
    __shared__ float w[392];                           // [oc*98 + ic*49 + ky*7 + kx]
    __shared__ float tile[8192];                       // [p 128][t 64], t rotated by p

    for (int i = threadIdx.x; i < 392; i += blockDim.x) w[i] = w0[i];

    int b   = blockIdx.x;                              // (n 8)(pyo 16)(pxb 8)
    int pxb = b & 7;
    int pyo = (b >> 3) & 15;
    int n   = b >> 7;

    int tid = threadIdx.x;
    int t4  = tid & 15;
    int pxl = (tid >> 4) & 7;
    int pr  = tid >> 7;                                // 0..3: row within tile
    int px  = pxb * 8 + pxl;
    int py  = pyo * 4 + pr;

    __syncthreads();                                   // weights ready

    float acc[4][4] = {};                              // [oc][t]
    bool interior = (pyo >= 1) & (pyo <= 14) & (pxb >= 1) & (pxb <= 6);
    if (interior) {
        for (int ic = 0; ic < 2; ++ic) {
            const float* in_c = pooled0 + (size_t)(n * 2 + ic) * 262144
                              + (size_t)t4 * 4 + (size_t)(px - 3) * 64;
            const float* wic = w + ic * 49;            // + oc*98 + ky*7 + kx
            #pragma unroll
            for (int ky = 0; ky < 7; ++ky) {
                const float* in_row = in_c + (size_t)(py - 3 + ky) * 4096;
                #pragma unroll
                for (int kx = 0; kx < 7; ++kx) {
                    float4 v = *(const float4*)(in_row + kx * 64);
                    #pragma unroll
                    for (int oc = 0; oc < 4; ++oc) {
                        float wd = wic[oc * 98 + ky * 7 + kx];
                        acc[oc][0] += v.x * wd;
                        acc[oc][1] += v.y * wd;
                        acc[oc][2] += v.z * wd;
                        acc[oc][3] += v.w * wd;
                    }
                }
            }
        }
    } else {
        for (int ic = 0; ic < 2; ++ic) {
            const float* in_c = pooled0 + (size_t)(n * 2 + ic) * 262144
                              + (size_t)t4 * 4;
            const float* wic = w + ic * 49;
            #pragma unroll
            for (int ky = 0; ky < 7; ++ky) {
                int iy = py - 3 + ky;
                if (iy < 0 || iy >= 64) continue;
                const float* in_row = in_c + (size_t)iy * 4096;
                #pragma unroll
                for (int kx = 0; kx < 7; ++kx) {
                    int ix = px + kx - 3;
                    if (ix < 0 || ix >= 64) continue;
                    float4 v = *(const float4*)(in_row + ix * 64);
                    #pragma unroll
                    for (int oc = 0; oc < 4; ++oc) {
                        float wd = wic[oc * 98 + ky * 7 + kx];
                        acc[oc][0] += v.x * wd;
                        acc[oc][1] += v.y * wd;
                        acc[oc][2] += v.z * wd;
                        acc[oc][3] += v.w * wd;
                    }
                }
            }
        }
    }
    // scatter to LDS, rotated: idx = p*64 + (t+p)&63
    #pragma unroll
    for (int oc = 0; oc < 4; ++oc) {
        int p = oc * 32 + pr * 8 + pxl;
        #pragma unroll
        for (int j = 0; j < 4; ++j) {
            int tt = t4 * 4 + j;
            tile[p * 64 + ((tt + p) & 63)] = acc[oc][j];
        }
    }
    __syncthreads();

    if (tid < 128) {
        int p   = tid;                                 // oc(2b at 5)|pyl(2b at 3)|pxl(3b)
        int oc  = p >> 5;
        int pxo = (p >> 2) & 1;
        float v = 0.f;
        unsigned int sp[16];
        const float* tp = tile + p * 64;
        #pragma unroll
        for (int i = 0; i < 16; ++i) {
            unsigned int wd = 0;
            #pragma unroll
            for (int j = 0; j < 4; ++j) {
                int t = i * 4 + j;
                float x = tp[(t + p) & 63];
                v += x;
                unsigned int s_ = (v >= 1.f) ? 1u : 0u;
                v -= (float)s_;
                wd += s_ << (8 * j);
            }
            sp[i] = wd;
        }
        // pool over dx (bits 0,1) and dy (bits 3,4); bytes can't carry
        #pragma unroll
        for (int i = 0; i < 16; ++i) {
            sp[i] += __shfl_xor(sp[i], 1);
            sp[i] += __shfl_xor(sp[i], 2);
            sp[i] += __shfl_xor(sp[i], 8);
            sp[i] += __shfl_xor(sp[i], 16);
        }
        int i = (p & 3) | (((p >> 3) & 3) << 2);       // member index 0..15
        unsigned int s = sp[i];
        float4 o = make_float4((float)(s & 255u)         * 0.0625f,
                               (float)((s >> 8)  & 255u) * 0.0625f,
                               (float)((s >> 16) & 255u) * 0.0625f,
                               (float)((s >> 24) & 255u) * 0.0625f);
        float* outp = pooled1 +
            (((size_t)(n * 4 + oc) * 16 + pyo) * 16 + (pxb * 2 + pxo)) * 64 + i * 4;
        *(float4*)outp = o;
    }
}

// ---------------------------------------------------------------------------
// K3 v3: conv7 pad3, ic=4 -> oc=8 on (8,4,16,16,t), FP32 taps.
// Same tap order (ic,ky,kx ascending). Each thread: 4 t (float4) x 4 oc.
// Grid: 256 blocks x 256.
__global__ __launch_bounds__(256) void conv1_kernel(
        const float* __restrict__ pooled1,
        const float* __restrict__ w1,
        float* __restrict__ h1) {
    __shared__ float w[1568];                          // (8,4,7,7)
    for (int i = threadIdx.x; i < 1568; i += blockDim.x) w[i] = w1[i];
    __syncthreads();

    int tid = blockIdx.x * blockDim.x + threadIdx.x;   // 65,536 threads
    int t4 = tid & 15;                                 // 4 t per thread
    int px = (tid >> 4) & 15;
    int py = (tid >> 8) & 15;
    int og = (tid >> 12) & 1;                          // oc group: og*4 .. og*4+3
    int n  = tid >> 13;                                // 0..7

    float acc[4][4] = {};                              // [oc4][t j]

    for (int ic = 0; ic < 4; ++ic) {
        const float* in_c = pooled1 + (size_t)(n * 4 + ic) * 16384 + t4 * 4;
        const float* wic = w + (size_t)og * 4 * 196 + ic * 49;  // + oc4*196 + ky*7 + kx
        #pragma unroll
        for (int ky = 0; ky < 7; ++ky) {
            int iy = py + ky - 3;
            if (iy < 0 || iy >= 16) continue;
            const float* in_row = in_c + (size_t)iy * 1024;
            #pragma unroll
            for (int kx = 0; kx < 7; ++kx) {
                int ix = px + kx - 3;
                if (ix < 0 || ix >= 16) continue;
                float4 v = *(const float4*)(in_row + ix * 64);
                #pragma unroll
                for (int oc4 = 0; oc4 < 4; ++oc4) {
                    float wd = wic[oc4 * 196 + ky * 7 + kx];
                    acc[oc4][0] += v.x * wd;
                    acc[oc4][1] += v.y * wd;
                    acc[oc4][2] += v.z * wd;
                    acc[oc4][3] += v.w * wd;
                }
            }
        }
    }
    size_t ob = (size_t)n * 131072 + (size_t)(og * 4) * 16384
              + (size_t)py * 1024 + px * 64 + t4 * 4;
    #pragma unroll
    for (int oc4 = 0; oc4 < 4; ++oc4) {
        float4 o = make_float4(acc[oc4][0], acc[oc4][1],
                               acc[oc4][2], acc[oc4][3]);
        *(float4*)(h1 + ob + (size_t)oc4 * 16384) = o;
    }
}

// ---------------------------------------------------------------------------
// K4: fused IAF1 + avgpool4 -> feat(n,128,t). Spikes never hit memory.
// (Already fp32; unchanged.)
__global__ __launch_bounds__(256) void iaf1_pool2_kernel(
        const float* __restrict__ h1, float* __restrict__ feat) {
    int b = blockIdx.x;                                // 64 = (n 8)(c 8)
    int c = b & 7;
    int n = b >> 3;
    int tid = threadIdx.x;
    int dx  = tid & 3;
    int dy  = (tid >> 2) & 3;
    int q   = tid >> 4;                                // 0..15 = pyo*4+pxo
    int pyo = q >> 2;
    int pxo = q & 3;
    int py  = pyo * 4 + dy;
    int px  = pxo * 4 + dx;

    const float4* p = (const float4*)(h1 +
        (((size_t)(n * 8 + c) * 16 + py) * 16 + px) * 64);

    float v = 0.f;
    unsigned int sp[16];
    #pragma unroll
    for (int i = 0; i < 16; ++i) {
        float4 x = p[i];
        unsigned int w = 0;
        #define STEP(j, e)                                                    \
        {   v += x.e;                                                         \
            unsigned int s_ = (v >= 1.f) ? 1u : 0u;                           \
            v -= (float)s_;                                                   \
            w += s_ << (8 * j); }
        STEP(0, x) STEP(1, y) STEP(2, z) STEP(3, w)
        #undef STEP
        sp[i] = w;
    }
    #pragma unroll
    for (int i = 0; i < 16; ++i) {
        sp[i] += __shfl_xor(sp[i], 1);
        sp[i] += __shfl_xor(sp[i], 2);
        sp[i] += __shfl_xor(sp[i], 4);
        sp[i] += __shfl_xor(sp[i], 8);
    }
    int i = tid & 15;
    unsigned int s = sp[i];
    float4 o = make_float4((float)(s & 255u)         * 0.0625f,
                           (float)((s >> 8)  & 255u) * 0.0625f,
                           (float)((s >> 16) & 255u) * 0.0625f,
                           (float)((s >> 24) & 255u) * 0.0625f);
    int f = c * 16 + q;
    *(float4*)(feat + ((size_t)n * 128 + f) * 64 + i * 4) = o;
}

// ---------------------------------------------------------------------------
// K5: linear. out(n,j,t) = sum_f wl[j,f] * feat[n,f,t], fp64 acc (trivial
// cost at 16 waves; keeps the final reduce maximally stable).
__global__ __launch_bounds__(64) void linear_kernel(
        const float* __restrict__ feat, const float* __restrict__ wl,
        float* __restrict__ out) {
    int tid = blockIdx.x * 64 + threadIdx.x;           // 1024 threads
    int t = tid & 63;
    int j = (tid >> 6) & 1;
    int n = tid >> 7;
    const float* fp = feat + (size_t)n * 128 * 64 + t;
    const float* wp = wl + j * 128;
    double acc = 0.0;
    for (int f = 0; f < 128; ++f)
        acc += (double)wp[f] * (double)fp[(size_t)f * 64];
    out[(size_t)(n * 2 + j) * 64 + t] = (float)acc;
}

// ---------------------------------------------------------------------------
extern "C" void kernel_launch(void* const* d_in, const int* in_sizes, int n_in,
                              void* d_out, int out_size, void* d_ws, size_t ws_size,
                              hipStream_t stream) {
    const float* inp = (const float*)d_in[0];
    const float* w0  = (const float*)d_in[1];
    const float* w1  = (const float*)d_in[2];
    const float* wl  = (const float*)d_in[3];
    float* out = (float*)d_out;
    float* ws  = (float*)d_ws;

    float* pooled0 = ws + OFF_P0;
    float* pooled1 = ws + OFF_P1;
    float* h1      = ws + OFF_H1;
    float* feat    = ws + OFF_FT;

    pool0_kernel<<<4096, 256, 0, stream>>>(inp, pooled0);
    conv0_iaf0_pool1_kernel<<<1024, 512, 0, stream>>>(pooled0, w0, pooled1);
    conv1_kernel<<<256, 256, 0, stream>>>(pooled1, w1, h1);
    iaf1_pool2_kernel<<<64, 256, 0, stream>>>(h1, feat);
    linear_kernel<<<16, 64, 0, stream>>>(feat, wl, out);
}

// Round 10
// 439.989 us; speedup vs baseline: 1.0715x; 1.0318x over previous
//
#include <hip/hip_runtime.h>

// Problem: ExodusModel_8564164788248
// inp: (8,2,256,256,64) f32, w0: (4,2,7,7), w1: (8,4,7,7), wl: (2,128)
// out: (8,2,64) f32
//
// SESSION FINDINGS (hardware-verified):
//  R8: K2 v1(256t) vs v2(512t) fp64: 459 vs 471 us — structure-insensitive.
//  R9: full fp32 conv: 454 us, absmax = 0.0 (!) — fp64 was NOT the wall
//      (fp64 ~spec rate, ~25 us total); our (ic,ky,kx)-ascending fp32 conv
//      is BIT-EXACT vs the XLA fp32 reference. A large kernel-invariant
//      constant (~320 us ≈ 2x 1.07GB workspace poison fills) dominates
//      dur_us; our kernels are ~134 us of it.
//  => R10: attack the biggest remaining kernel cost: K2's 822 MB of L3-served
//     tap re-reads (16.8 MB pooled0, 11x amplification). LDS-stage the input
//     tile (zero-filled halo, branch-free taps). Global traffic -> 73 MB.
//     Zero-tap adds are bitwise identity (acc starts +0, can never be -0),
//     tap order unchanged => absmax stays 0.0.
//
// Workspace layout (floats):
//   pooled0 : (8,2,64,64,64)  = 4,194,304   @ 0
//   pooled1 : (8,4,16,16,64)  =   524,288   @ 12,582,912
//   h1      : (8,8,16,16,64)  = 1,048,576   @ 13,107,200  (s1 never stored)
//   feat    : (8,128,64)      =    65,536   @ 14,155,776

#define OFF_P0   0
#define OFF_P1   12582912
#define OFF_H1   13107200
#define OFF_FT   14155776

typedef float f32x4 __attribute__((ext_vector_type(4)));

// ---------------------------------------------------------------------------
// K1: avgpool 4x4 on raw input. (n,c,256,256,t) -> (n,c,64,64,t)
// float4 on stride-1 t axis; fp32 accumulate + *0.0625. HBM-floor bound.
__global__ __launch_bounds__(256) void pool0_kernel(
        const float* __restrict__ inp, float* __restrict__ out) {
    int tid = blockIdx.x * blockDim.x + threadIdx.x;   // 1,048,576 threads
    int t4 = tid & 15;
    int px = (tid >> 4) & 63;
    int py = (tid >> 10) & 63;
    int nc = tid >> 16;                                // n*2+c, 0..15
    const float* base = inp + (size_t)nc * 4194304 + (size_t)t4 * 4;
    int y0 = py * 4, x0 = px * 4;
    float a0 = 0.f, a1 = 0.f, a2 = 0.f, a3 = 0.f;
    #pragma unroll
    for (int dy = 0; dy < 4; ++dy) {
        const float* row = base + ((size_t)(y0 + dy) * 256 + x0) * 64;
        #pragma unroll
        for (int dx = 0; dx < 4; ++dx) {
            const f32x4 v = __builtin_nontemporal_load(
                (const f32x4*)(row + dx * 64));
            a0 += v.x; a1 += v.y; a2 += v.z; a3 += v.w;
        }
    }
    float4 o = make_float4(a0 * 0.0625f, a1 * 0.0625f,
                           a2 * 0.0625f, a3 * 0.0625f);
    ((float4*)out)[tid] = o;
}

// ---------------------------------------------------------------------------
// K2 v4: FUSED conv0 + IAF0 + pool1, FP32, LDS-staged input.
// Grid = 1024 blocks x 512 threads, 39.6 KB LDS (ins aliases tile).
//
// Per block tile: oc 0..3, py = pyo*4..+3, px = pxb*8..+7, t 0..63.
// Stage (per ic, sequential): input rows py0-3..py0+6, px pxb*8-3..+10,
// all 64 t, ZERO-FILLED outside [0,64) -> accumulate loop is branch-free
// for ALL blocks. ins layout [row 10][px 14][t 64] with px-stride 68
// (t-pad 4) for bank spread. Tap order per output: (ic,ky,kx) ascending ==
// R9's bit-exact version; zero-taps are bitwise identity (+0 adds).
// Phase 2 (IAF+pool): UNCHANGED (exact reference fp32 IAF sequence).
// ins (9520 f) is dead before tile (8192 f) is written => aliased buffer,
// barrier between.
__global__ __launch_bounds__(512) void conv0_iaf0_pool1_kernel(
        const float* __restrict__ pooled0, const float* __restrict__ w0,
        float* __restrict__ pooled1) {
    __shared__ float w[392];                           // [oc*98 + ic*49 + ky*7 + kx]
    __shared__ float smem[9520];                       // ins [10][14][68-pad] / tile alias
    float* ins  = smem;
    float* tile = smem;                                // [p 128][t 64], t rotated by p

    for (int i = threadIdx.x; i < 392; i += blockDim.x) w[i] = w0[i];

    int b   = blockIdx.x;                              // (n 8)(pyo 16)(pxb 8)
    int pxb = b & 7;
    int pyo = (b >> 3) & 15;
    int n   = b >> 7;

    int tid = threadIdx.x;
    int t4  = tid & 15;
    int pxl = (tid >> 4) & 7;
    int pr  = tid >> 7;                                // 0..3: row within tile
    int py0 = pyo * 4;

    float acc[4][4] = {};                              // [oc][t]

    for (int ic = 0; ic < 2; ++ic) {
        __syncthreads();       // ic0: w ready; ic1: prev accumulate done
        // ---- stage: 2240 float4 chunks = [row 10][px 14][tt 16] ----
        const float* src = pooled0 + (size_t)(n * 2 + ic) * 262144;
        for (int c = tid; c < 2240; c += 512) {
            int row = c / 224;                         // 14*16 chunks per row
            int rem = c - row * 224;
            int px  = rem >> 4;
            int tt  = rem & 15;
            int iy  = py0 - 3 + row;
            int ix  = pxb * 8 - 3 + px;
            f32x4 v = {0.f, 0.f, 0.f, 0.f};
            if (iy >= 0 && iy < 64 && ix >= 0 && ix < 64)
                v = *(const f32x4*)(src + (size_t)iy * 4096 + ix * 64 + tt * 4);
            *(f32x4*)(ins + row * 952 + px * 68 + tt * 4) = v;
        }
        __syncthreads();       // tile staged
        // ---- accumulate: branch-free 7x7 taps from LDS ----
        const float* wic = w + ic * 49;                // + oc*98 + ky*7 + kx
        #pragma unroll
        for (int ky = 0; ky < 7; ++ky) {
            const float* rbase = ins + (pr + ky) * 952 + pxl * 68 + t4 * 4;
            #pragma unroll
            for (int kx = 0; kx < 7; ++kx) {
                f32x4 v = *(const f32x4*)(rbase + kx * 68);
                #pragma unroll
                for (int oc = 0; oc < 4; ++oc) {
                    float wd = wic[oc * 98 + ky * 7 + kx];
                    acc[oc][0] += v.x * wd;
                    acc[oc][1] += v.y * wd;
                    acc[oc][2] += v.z * wd;
                    acc[oc][3] += v.w * wd;
                }
            }
        }
    }
    __syncthreads();           // ins reads done everywhere; safe to alias
    // scatter to LDS, rotated: idx = p*64 + (t+p)&63
    #pragma unroll
    for (int oc = 0; oc < 4; ++oc) {
        int p = oc * 32 + pr * 8 + pxl;
        #pragma unroll
        for (int j = 0; j < 4; ++j) {
            int tt = t4 * 4 + j;
            tile[p * 64 + ((tt + p) & 63)] = acc[oc][j];
        }
    }
    __syncthreads();

    if (tid < 128) {
        int p   = tid;                                 // oc(2b at 5)|pyl(2b at 3)|pxl(3b)
        int oc  = p >> 5;
        int pxo = (p >> 2) & 1;
        float v = 0.f;
        unsigned int sp[16];
        const float* tp = tile + p * 64;
        #pragma unroll
        for (int i = 0; i < 16; ++i) {
            unsigned int wd = 0;
            #pragma unroll
            for (int j = 0; j < 4; ++j) {
                int t = i * 4 + j;
                float x = tp[(t + p) & 63];
                v += x;
                unsigned int s_ = (v >= 1.f) ? 1u : 0u;
                v -= (float)s_;
                wd += s_ << (8 * j);
            }
            sp[i] = wd;
        }
        // pool over dx (bits 0,1) and dy (bits 3,4); bytes can't carry
        #pragma unroll
        for (int i = 0; i < 16; ++i) {
            sp[i] += __shfl_xor(sp[i], 1);
            sp[i] += __shfl_xor(sp[i], 2);
            sp[i] += __shfl_xor(sp[i], 8);
            sp[i] += __shfl_xor(sp[i], 16);
        }
        int i = (p & 3) | (((p >> 3) & 3) << 2);       // member index 0..15
        unsigned int s = sp[i];
        float4 o = make_float4((float)(s & 255u)         * 0.0625f,
                               (float)((s >> 8)  & 255u) * 0.0625f,
                               (float)((s >> 16) & 255u) * 0.0625f,
                               (float)((s >> 24) & 255u) * 0.0625f);
        float* outp = pooled1 +
            (((size_t)(n * 4 + oc) * 16 + pyo) * 16 + (pxb * 2 + pxo)) * 64 + i * 4;
        *(float4*)outp = o;
    }
}

// ---------------------------------------------------------------------------
// K3 v3: conv7 pad3, ic=4 -> oc=8 on (8,4,16,16,t), FP32 taps.
// Tap order (ic,ky,kx ascending). Each thread: 4 t (float4) x 4 oc.
// Grid: 256 blocks x 256. (Unchanged from R9 bit-exact version.)
__global__ __launch_bounds__(256) void conv1_kernel(
        const float* __restrict__ pooled1,
        const float* __restrict__ w1,
        float* __restrict__ h1) {
    __shared__ float w[1568];                          // (8,4,7,7)
    for (int i = threadIdx.x; i < 1568; i += blockDim.x) w[i] = w1[i];
    __syncthreads();

    int tid = blockIdx.x * blockDim.x + threadIdx.x;   // 65,536 threads
    int t4 = tid & 15;                                 // 4 t per thread
    int px = (tid >> 4) & 15;
    int py = (tid >> 8) & 15;
    int og = (tid >> 12) & 1;                          // oc group: og*4 .. og*4+3
    int n  = tid >> 13;                                // 0..7

    float acc[4][4] = {};                              // [oc4][t j]

    for (int ic = 0; ic < 4; ++ic) {
        const float* in_c = pooled1 + (size_t)(n * 4 + ic) * 16384 + t4 * 4;
        const float* wic = w + (size_t)og * 4 * 196 + ic * 49;  // + oc4*196 + ky*7 + kx
        #pragma unroll
        for (int ky = 0; ky < 7; ++ky) {
            int iy = py + ky - 3;
            if (iy < 0 || iy >= 16) continue;
            const float* in_row = in_c + (size_t)iy * 1024;
            #pragma unroll
            for (int kx = 0; kx < 7; ++kx) {
                int ix = px + kx - 3;
                if (ix < 0 || ix >= 16) continue;
                float4 v = *(const float4*)(in_row + ix * 64);
                #pragma unroll
                for (int oc4 = 0; oc4 < 4; ++oc4) {
                    float wd = wic[oc4 * 196 + ky * 7 + kx];
                    acc[oc4][0] += v.x * wd;
                    acc[oc4][1] += v.y * wd;
                    acc[oc4][2] += v.z * wd;
                    acc[oc4][3] += v.w * wd;
                }
            }
        }
    }
    size_t ob = (size_t)n * 131072 + (size_t)(og * 4) * 16384
              + (size_t)py * 1024 + px * 64 + t4 * 4;
    #pragma unroll
    for (int oc4 = 0; oc4 < 4; ++oc4) {
        float4 o = make_float4(acc[oc4][0], acc[oc4][1],
                               acc[oc4][2], acc[oc4][3]);
        *(float4*)(h1 + ob + (size_t)oc4 * 16384) = o;
    }
}

// ---------------------------------------------------------------------------
// K4: fused IAF1 + avgpool4 -> feat(n,128,t). Spikes never hit memory.
__global__ __launch_bounds__(256) void iaf1_pool2_kernel(
        const float* __restrict__ h1, float* __restrict__ feat) {
    int b = blockIdx.x;                                // 64 = (n 8)(c 8)
    int c = b & 7;
    int n = b >> 3;
    int tid = threadIdx.x;
    int dx  = tid & 3;
    int dy  = (tid >> 2) & 3;
    int q   = tid >> 4;                                // 0..15 = pyo*4+pxo
    int pyo = q >> 2;
    int pxo = q & 3;
    int py  = pyo * 4 + dy;
    int px  = pxo * 4 + dx;

    const float4* p = (const float4*)(h1 +
        (((size_t)(n * 8 + c) * 16 + py) * 16 + px) * 64);

    float v = 0.f;
    unsigned int sp[16];
    #pragma unroll
    for (int i = 0; i < 16; ++i) {
        float4 x = p[i];
        unsigned int w = 0;
        #define STEP(j, e)                                                    \
        {   v += x.e;                                                         \
            unsigned int s_ = (v >= 1.f) ? 1u : 0u;                           \
            v -= (float)s_;                                                   \
            w += s_ << (8 * j); }
        STEP(0, x) STEP(1, y) STEP(2, z) STEP(3, w)
        #undef STEP
        sp[i] = w;
    }
    #pragma unroll
    for (int i = 0; i < 16; ++i) {
        sp[i] += __shfl_xor(sp[i], 1);
        sp[i] += __shfl_xor(sp[i], 2);
        sp[i] += __shfl_xor(sp[i], 4);
        sp[i] += __shfl_xor(sp[i], 8);
    }
    int i = tid & 15;
    unsigned int s = sp[i];
    float4 o = make_float4((float)(s & 255u)         * 0.0625f,
                           (float)((s >> 8)  & 255u) * 0.0625f,
                           (float)((s >> 16) & 255u) * 0.0625f,
                           (float)((s >> 24) & 255u) * 0.0625f);
    int f = c * 16 + q;
    *(float4*)(feat + ((size_t)n * 128 + f) * 64 + i * 4) = o;
}

// ---------------------------------------------------------------------------
// K5: linear. out(n,j,t) = sum_f wl[j,f] * feat[n,f,t], fp64 acc (trivial
// cost; matched reference bit-exactly in R9).
__global__ __launch_bounds__(64) void linear_kernel(
        const float* __restrict__ feat, const float* __restrict__ wl,
        float* __restrict__ out) {
    int tid = blockIdx.x * 64 + threadIdx.x;           // 1024 threads
    int t = tid & 63;
    int j = (tid >> 6) & 1;
    int n = tid >> 7;
    const float* fp = feat + (size_t)n * 128 * 64 + t;
    const float* wp = wl + j * 128;
    double acc = 0.0;
    for (int f = 0; f < 128; ++f)
        acc += (double)wp[f] * (double)fp[(size_t)f * 64];
    out[(size_t)(n * 2 + j) * 64 + t] = (float)acc;
}

// ---------------------------------------------------------------------------
extern "C" void kernel_launch(void* const* d_in, const int* in_sizes, int n_in,
                              void* d_out, int out_size, void* d_ws, size_t ws_size,
                              hipStream_t stream) {
    const float* inp = (const float*)d_in[0];
    const float* w0  = (const float*)d_in[1];
    const float* w1  = (const float*)d_in[2];
    const float* wl  = (const float*)d_in[3];
    float* out = (float*)d_out;
    float* ws  = (float*)d_ws;

    float* pooled0 = ws + OFF_P0;
    float* pooled1 = ws + OFF_P1;
    float* h1      = ws + OFF_H1;
    float* feat    = ws + OFF_FT;

    pool0_kernel<<<4096, 256, 0, stream>>>(inp, pooled0);
    conv0_iaf0_pool1_kernel<<<1024, 512, 0, stream>>>(pooled0, w0, pooled1);
    conv1_kernel<<<256, 256, 0, stream>>>(pooled1, w1, h1);
    iaf1_pool2_kernel<<<64, 256, 0, stream>>>(h1, feat);
    linear_kernel<<<16, 64, 0, stream>>>(feat, wl, out);
}

// Round 13
// 429.597 us; speedup vs baseline: 1.0975x; 1.0242x over previous
//
#include <hip/hip_runtime.h>

// Problem: ExodusModel_8564164788248
// inp: (8,2,256,256,64) f32, w0: (4,2,7,7), w1: (8,4,7,7), wl: (2,128)
// out: (8,2,64) f32
//
// SESSION FINDINGS (hardware-verified):
//  R8: fp64 conv 256t vs 512t: 459 vs 471 us — structure-insensitive.
//  R9: fp32 conv: 454 us, absmax = 0.0 — conv FMA rate was never the wall;
//      our (ic,ky,kx)-ascending fp32 conv is BIT-EXACT vs the XLA reference.
//  R10: LDS-staged K2 input: 440 us (-14). Data traffic wasn't the wall
//      either.
//  => R11 theory: K2 is LDS-PIPE-bound on WEIGHT BROADCASTS: 392 uniform
//     ds_read_b32 per thread (~30 us chip-wide) + 98 data b128 (~15 us)
//     vs only 10.5 us VALU. Fix: weights via wave-uniform GLOBAL reads
//     (SGPR base + constant offsets -> s_load, SMEM pipe), LDS w[] deleted
//     in K2 and K3. Same bits, same tap order => absmax stays 0.0.
//
// Workspace layout (floats):
//   pooled0 : (8,2,64,64,64)  = 4,194,304   @ 0
//   pooled1 : (8,4,16,16,64)  =   524,288   @ 12,582,912
//   h1      : (8,8,16,16,64)  = 1,048,576   @ 13,107,200  (s1 never stored)
//   feat    : (8,128,64)      =    65,536   @ 14,155,776

#define OFF_P0   0
#define OFF_P1   12582912
#define OFF_H1   13107200
#define OFF_FT   14155776

typedef float f32x4 __attribute__((ext_vector_type(4)));

// ---------------------------------------------------------------------------
// K1: avgpool 4x4 on raw input. (n,c,256,256,t) -> (n,c,64,64,t)
// float4 on stride-1 t axis; fp32 accumulate + *0.0625. HBM-floor bound
// (~285 MB @ ~6.7 TB/s achieved => ~43 us).
__global__ __launch_bounds__(256) void pool0_kernel(
        const float* __restrict__ inp, float* __restrict__ out) {
    int tid = blockIdx.x * blockDim.x + threadIdx.x;   // 1,048,576 threads
    int t4 = tid & 15;
    int px = (tid >> 4) & 63;
    int py = (tid >> 10) & 63;
    int nc = tid >> 16;                                // n*2+c, 0..15
    const float* base = inp + (size_t)nc * 4194304 + (size_t)t4 * 4;
    int y0 = py * 4, x0 = px * 4;
    float a0 = 0.f, a1 = 0.f, a2 = 0.f, a3 = 0.f;
    #pragma unroll
    for (int dy = 0; dy < 4; ++dy) {
        const float* row = base + ((size_t)(y0 + dy) * 256 + x0) * 64;
        #pragma unroll
        for (int dx = 0; dx < 4; ++dx) {
            const f32x4 v = __builtin_nontemporal_load(
                (const f32x4*)(row + dx * 64));
            a0 += v.x; a1 += v.y; a2 += v.z; a3 += v.w;
        }
    }
    float4 o = make_float4(a0 * 0.0625f, a1 * 0.0625f,
                           a2 * 0.0625f, a3 * 0.0625f);
    ((float4*)out)[tid] = o;
}

// ---------------------------------------------------------------------------
// K2 v5: FUSED conv0 + IAF0 + pool1, FP32, LDS-staged input, SCALAR weights.
// Grid = 1024 blocks x 512 threads, 38 KB LDS (ins aliases tile).
//
// Weights: read straight from w0 (global) with wave-uniform indices
// (SGPR kernarg base + unrolled-constant offset) -> s_load on the SMEM
// pipe. No LDS weight buffer => LDS pipe only carries the 98 data b128
// reads per thread (was 98 + 392 broadcasts).
// Stage (per ic): rows py0-3..+6, px pxb*8-3..+10, all t, zero-filled halo
// -> branch-free taps for all blocks. Tap order (ic,ky,kx) ascending ==
// R9/R10 bit-exact versions; zero-taps are bitwise identity.
// Phase 2 (IAF+pool): UNCHANGED exact reference fp32 IAF sequence.
__global__ __launch_bounds__(512) void conv0_iaf0_pool1_kernel(
        const float* __restrict__ pooled0, const float* __restrict__ w0,
        float* __restrict__ pooled1) {
    __shared__ float smem[9520];                       // ins [10][14][68] / tile alias
    float* ins  = smem;
    float* tile = smem;                                // [p 128][t 64], t rotated by p

    int b   = blockIdx.x;                              // (n 8)(pyo 16)(pxb 8)
    int pxb = b & 7;
    int pyo = (b >> 3) & 15;
    int n   = b >> 7;

    int tid = threadIdx.x;
    int t4  = tid & 15;
    int pxl = (tid >> 4) & 7;
    int pr  = tid >> 7;                                // 0..3: row within tile
    int py0 = pyo * 4;

    float acc[4][4] = {};                              // [oc][t]

    for (int ic = 0; ic < 2; ++ic) {
        __syncthreads();       // ic1: prev accumulate done (ic0: harmless)
        // ---- stage: 2240 float4 chunks = [row 10][px 14][tt 16] ----
        const float* src = pooled0 + (size_t)(n * 2 + ic) * 262144;
        for (int c = tid; c < 2240; c += 512) {
            int row = c / 224;                         // 14*16 chunks per row
            int rem = c - row * 224;
            int px  = rem >> 4;
            int tt  = rem & 15;
            int iy  = py0 - 3 + row;
            int ix  = pxb * 8 - 3 + px;
            f32x4 v = {0.f, 0.f, 0.f, 0.f};
            if (iy >= 0 && iy < 64 && ix >= 0 && ix < 64)
                v = *(const f32x4*)(src + (size_t)iy * 4096 + ix * 64 + tt * 4);
            *(f32x4*)(ins + row * 952 + px * 68 + tt * 4) = v;
        }
        __syncthreads();       // tile staged
        // ---- accumulate: branch-free 7x7 taps, weights via s_load ----
        const float* wic = w0 + ic * 49;               // + oc*98 + ky*7 + kx (uniform)
        #pragma unroll
        for (int ky = 0; ky < 7; ++ky) {
            const float* rbase = ins + (pr + ky) * 952 + pxl * 68 + t4 * 4;
            #pragma unroll
            for (int kx = 0; kx < 7; ++kx) {
                f32x4 v = *(const f32x4*)(rbase + kx * 68);
                #pragma unroll
                for (int oc = 0; oc < 4; ++oc) {
                    float wd = wic[oc * 98 + ky * 7 + kx];
                    acc[oc][0] += v.x * wd;
                    acc[oc][1] += v.y * wd;
                    acc[oc][2] += v.z * wd;
                    acc[oc][3] += v.w * wd;
                }
            }
        }
    }
    __syncthreads();           // ins reads done everywhere; safe to alias
    // scatter to LDS, rotated: idx = p*64 + (t+p)&63
    #pragma unroll
    for (int oc = 0; oc < 4; ++oc) {
        int p = oc * 32 + pr * 8 + pxl;
        #pragma unroll
        for (int j = 0; j < 4; ++j) {
            int tt = t4 * 4 + j;
            tile[p * 64 + ((tt + p) & 63)] = acc[oc][j];
        }
    }
    __syncthreads();

    if (tid < 128) {
        int p   = tid;                                 // oc(2b at 5)|pyl(2b at 3)|pxl(3b)
        int oc  = p >> 5;
        int pxo = (p >> 2) & 1;
        float v = 0.f;
        unsigned int sp[16];
        const float* tp = tile + p * 64;
        #pragma unroll
        for (int i = 0; i < 16; ++i) {
            unsigned int wd = 0;
            #pragma unroll
            for (int j = 0; j < 4; ++j) {
                int t = i * 4 + j;
                float x = tp[(t + p) & 63];
                v += x;
                unsigned int s_ = (v >= 1.f) ? 1u : 0u;
                v -= (float)s_;
                wd += s_ << (8 * j);
            }
            sp[i] = wd;
        }
        // pool over dx (bits 0,1) and dy (bits 3,4); bytes can't carry
        #pragma unroll
        for (int i = 0; i < 16; ++i) {
            sp[i] += __shfl_xor(sp[i], 1);
            sp[i] += __shfl_xor(sp[i], 2);
            sp[i] += __shfl_xor(sp[i], 8);
            sp[i] += __shfl_xor(sp[i], 16);
        }
        int i = (p & 3) | (((p >> 3) & 3) << 2);       // member index 0..15
        unsigned int s = sp[i];
        float4 o = make_float4((float)(s & 255u)         * 0.0625f,
                               (float)((s >> 8)  & 255u) * 0.0625f,
                               (float)((s >> 16) & 255u) * 0.0625f,
                               (float)((s >> 24) & 255u) * 0.0625f);
        float* outp = pooled1 +
            (((size_t)(n * 4 + oc) * 16 + pyo) * 16 + (pxb * 2 + pxo)) * 64 + i * 4;
        *(float4*)outp = o;
    }
}

// ---------------------------------------------------------------------------
// K3 v4: conv7 pad3, ic=4 -> oc=8 on (8,4,16,16,t), FP32, SCALAR weights.
// og is block-uniform (bit 12 of tid comes from blockIdx) => weight index
// is SGPR-uniform -> s_load. No LDS. Tap order (ic,ky,kx) ascending ==
// R9 bit-exact version. Each thread: 4 t (float4) x 4 oc.
// Grid: 256 blocks x 256.
__global__ __launch_bounds__(256) void conv1_kernel(
        const float* __restrict__ pooled1,
        const float* __restrict__ w1,
        float* __restrict__ h1) {
    int tid = blockIdx.x * blockDim.x + threadIdx.x;   // 65,536 threads
    int t4 = tid & 15;                                 // 4 t per thread
    int px = (tid >> 4) & 15;
    int py = (tid >> 8) & 15;
    int og = (tid >> 12) & 1;                          // oc group: og*4 .. og*4+3
    int n  = tid >> 13;                                // 0..7

    float acc[4][4] = {};                              // [oc4][t j]

    for (int ic = 0; ic < 4; ++ic) {
        const float* in_c = pooled1 + (size_t)(n * 4 + ic) * 16384 + t4 * 4;
        const float* wic = w1 + (size_t)og * 4 * 196 + ic * 49;  // + oc4*196 + ky*7 + kx
        #pragma unroll
        for (int ky = 0; ky < 7; ++ky) {
            int iy = py + ky - 3;
            if (iy < 0 || iy >= 16) continue;
            const float* in_row = in_c + (size_t)iy * 1024;
            #pragma unroll
            for (int kx = 0; kx < 7; ++kx) {
                int ix = px + kx - 3;
                if (ix < 0 || ix >= 16) continue;
                float4 v = *(const float4*)(in_row + ix * 64);
                #pragma unroll
                for (int oc4 = 0; oc4 < 4; ++oc4) {
                    float wd = wic[oc4 * 196 + ky * 7 + kx];
                    acc[oc4][0] += v.x * wd;
                    acc[oc4][1] += v.y * wd;
                    acc[oc4][2] += v.z * wd;
                    acc[oc4][3] += v.w * wd;
                }
            }
        }
    }
    size_t ob = (size_t)n * 131072 + (size_t)(og * 4) * 16384
              + (size_t)py * 1024 + px * 64 + t4 * 4;
    #pragma unroll
    for (int oc4 = 0; oc4 < 4; ++oc4) {
        float4 o = make_float4(acc[oc4][0], acc[oc4][1],
                               acc[oc4][2], acc[oc4][3]);
        *(float4*)(h1 + ob + (size_t)oc4 * 16384) = o;
    }
}

// ---------------------------------------------------------------------------
// K4: fused IAF1 + avgpool4 -> feat(n,128,t). Spikes never hit memory.
__global__ __launch_bounds__(256) void iaf1_pool2_kernel(
        const float* __restrict__ h1, float* __restrict__ feat) {
    int b = blockIdx.x;                                // 64 = (n 8)(c 8)
    int c = b & 7;
    int n = b >> 3;
    int tid = threadIdx.x;
    int dx  = tid & 3;
    int dy  = (tid >> 2) & 3;
    int q   = tid >> 4;                                // 0..15 = pyo*4+pxo
    int pyo = q >> 2;
    int pxo = q & 3;
    int py  = pyo * 4 + dy;
    int px  = pxo * 4 + dx;

    const float4* p = (const float4*)(h1 +
        (((size_t)(n * 8 + c) * 16 + py) * 16 + px) * 64);

    float v = 0.f;
    unsigned int sp[16];
    #pragma unroll
    for (int i = 0; i < 16; ++i) {
        float4 x = p[i];
        unsigned int w = 0;
        #define STEP(j, e)                                                    \
        {   v += x.e;                                                         \
            unsigned int s_ = (v >= 1.f) ? 1u : 0u;                           \
            v -= (float)s_;                                                   \
            w += s_ << (8 * j); }
        STEP(0, x) STEP(1, y) STEP(2, z) STEP(3, w)
        #undef STEP
        sp[i] = w;
    }
    #pragma unroll
    for (int i = 0; i < 16; ++i) {
        sp[i] += __shfl_xor(sp[i], 1);
        sp[i] += __shfl_xor(sp[i], 2);
        sp[i] += __shfl_xor(sp[i], 4);
        sp[i] += __shfl_xor(sp[i], 8);
    }
    int i = tid & 15;
    unsigned int s = sp[i];
    float4 o = make_float4((float)(s & 255u)         * 0.0625f,
                           (float)((s >> 8)  & 255u) * 0.0625f,
                           (float)((s >> 16) & 255u) * 0.0625f,
                           (float)((s >> 24) & 255u) * 0.0625f);
    int f = c * 16 + q;
    *(float4*)(feat + ((size_t)n * 128 + f) * 64 + i * 4) = o;
}

// ---------------------------------------------------------------------------
// K5: linear. out(n,j,t) = sum_f wl[j,f] * feat[n,f,t], fp64 acc (trivial
// cost; matched reference bit-exactly since R9).
__global__ __launch_bounds__(64) void linear_kernel(
        const float* __restrict__ feat, const float* __restrict__ wl,
        float* __restrict__ out) {
    int tid = blockIdx.x * 64 + threadIdx.x;           // 1024 threads
    int t = tid & 63;
    int j = (tid >> 6) & 1;
    int n = tid >> 7;
    const float* fp = feat + (size_t)n * 128 * 64 + t;
    const float* wp = wl + j * 128;
    double acc = 0.0;
    for (int f = 0; f < 128; ++f)
        acc += (double)wp[f] * (double)fp[(size_t)f * 64];
    out[(size_t)(n * 2 + j) * 64 + t] = (float)acc;
}

// ---------------------------------------------------------------------------
extern "C" void kernel_launch(void* const* d_in, const int* in_sizes, int n_in,
                              void* d_out, int out_size, void* d_ws, size_t ws_size,
                              hipStream_t stream) {
    const float* inp = (const float*)d_in[0];
    const float* w0  = (const float*)d_in[1];
    const float* w1  = (const float*)d_in[2];
    const float* wl  = (const float*)d_in[3];
    float* out = (float*)d_out;
    float* ws  = (float*)d_ws;

    float* pooled0 = ws + OFF_P0;
    float* pooled1 = ws + OFF_P1;
    float* h1      = ws + OFF_H1;
    float* feat    = ws + OFF_FT;

    pool0_kernel<<<4096, 256, 0, stream>>>(inp, pooled0);
    conv0_iaf0_pool1_kernel<<<1024, 512, 0, stream>>>(pooled0, w0, pooled1);
    conv1_kernel<<<256, 256, 0, stream>>>(pooled1, w1, h1);
    iaf1_pool2_kernel<<<64, 256, 0, stream>>>(h1, feat);
    linear_kernel<<<16, 64, 0, stream>>>(feat, wl, out);
}